// Round 1
// baseline (1085.397 us; speedup 1.0000x reference)
//
#include <hip/hip_runtime.h>

// DNAMite GAM: 64 per-feature MLPs (32->128->128->1) + 2016 per-pair MLPs
// (64->128->128->1) over batch 512, z-weighted sum -> out[512].
// Round 0: correct fp32 baseline, register-tiled vector-ALU GEMMs.

constexpr int Bsz  = 512;
constexpr int NF   = 64;
constexpr int NE   = 32;
constexpr int NH   = 128;
constexpr int NP   = 2016;
constexpr int NBLK = NP + NF;   // 2080 group blocks
constexpr int BT   = 64;        // batch tile
constexpr int NCH  = 32;        // atomic accumulation chunks (ws = 32*512 floats = 64 KB)
constexpr int LDT  = 68;        // padded leading dim (multiple of 4 -> aligned float4)

__device__ __forceinline__ float smoothz(float z) {
  // gamma = 1: s = -2 z^3 + 1.5 z + 0.5, clamped outside [-0.5, 0.5]
  float s = fmaf(-2.0f * z * z, z, fmaf(1.5f, z, 0.5f));
  if (z <= -0.5f) s = 0.0f;
  if (z >=  0.5f) s = 1.0f;
  return s;
}

__global__ void zero_ws_kernel(float* __restrict__ ws) {
  ws[blockIdx.x * 256 + threadIdx.x] = 0.0f;
}

__global__ __launch_bounds__(256, 3) void fused_groups_kernel(
    const int* __restrict__ mains, const int* __restrict__ pairs,
    const float* __restrict__ emb,
    const float* __restrict__ mw0, const float* __restrict__ mw1,
    const float* __restrict__ mw2, const float* __restrict__ mb0,
    const float* __restrict__ mb1, const float* __restrict__ mb2,
    const float* __restrict__ z_main,
    const float* __restrict__ pw0, const float* __restrict__ pw1,
    const float* __restrict__ pw2, const float* __restrict__ pb0,
    const float* __restrict__ pb1, const float* __restrict__ pb2,
    const float* __restrict__ z_pairs,
    const int* __restrict__ pairs_list, const int* __restrict__ foff,
    float* __restrict__ ws) {
  // Transposed activation tiles: [k][b] so GEMM A-reads are aligned float4
  __shared__ float sA[2 * NE][LDT];  // layer-0 input, K<=64
  __shared__ float sH[NH][LDT];      // layer-1 input (H1), K=128

  const int t  = threadIdx.x;
  const int tl = t & 15;   // l-group: this thread's 8 output columns = tl*8..tl*8+7
  const int tb = t >> 4;   // b-group: this thread's 4 batch rows   = tb*4..tb*4+3
  const int g  = blockIdx.x;
  const bool is_pair = (g < NP);

  const float *W0, *W1, *w2p, *bv0, *bv1;
  float b2s, z;
  int K0, off0 = 0, off1 = 0, fid = 0;
  if (is_pair) {
    W0  = pw0 + (size_t)g * (2 * NE * NH);
    W1  = pw1 + (size_t)g * (NH * NH);
    w2p = pw2 + (size_t)g * NH;
    bv0 = pb0 + (size_t)g * NH;
    bv1 = pb1 + (size_t)g * NH;
    b2s = pb2[g];
    z   = smoothz(z_pairs[g]);
    K0  = 2 * NE;
    int f0 = pairs_list[2 * g + 0];
    int f1 = pairs_list[2 * g + 1];
    off0 = foff[f0];
    off1 = foff[f1];
  } else {
    fid = g - NP;
    W0  = mw0 + (size_t)fid * (NE * NH);
    W1  = mw1 + (size_t)fid * (NH * NH);
    w2p = mw2 + (size_t)fid * NH;
    bv0 = mb0 + (size_t)fid * NH;
    bv1 = mb1 + (size_t)fid * NH;
    b2s = mb2[fid];
    z   = smoothz(z_main[fid]);
    K0  = NE;
    off0 = foff[fid];
  }

  // Preload per-thread biases and w2 slice (8 floats each)
  float bias0[8], bias1[8], wv2[8];
  {
    const float4* p0 = (const float4*)(bv0 + tl * 8);
    const float4* p1 = (const float4*)(bv1 + tl * 8);
    const float4* p2 = (const float4*)(w2p + tl * 8);
    *(float4*)&bias0[0] = p0[0]; *(float4*)&bias0[4] = p0[1];
    *(float4*)&bias1[0] = p1[0]; *(float4*)&bias1[4] = p1[1];
    *(float4*)&wv2[0]   = p2[0]; *(float4*)&wv2[4]   = p2[1];
  }

  for (int tile = 0; tile < Bsz / BT; ++tile) {
    const int bbase = tile * BT;
    __syncthreads();  // previous iteration's sA/sH reads complete

    // ---- stage layer-0 input, transposed: sA[k][b_local] ----
    {
      const int br = t & 63;   // batch row within tile
      const int q  = t >> 6;   // 16-column chunk: 0..3
      const int b  = bbase + br;
      int idx;
      if (is_pair) {
        const int which = q >> 1;  // 0: first feature (cols 0..31), 1: second (32..63)
        const int bin = pairs[(size_t)b * (NP * 2) + 2 * g + which];
        idx = bin + (which ? off1 : off0);
      } else {
        idx = mains[b * NF + fid] + off0;  // q>=2 writes unread rows (K0=32)
      }
      const float* er = emb + (size_t)idx * NE + (q & 1) * 16;
      float ev[16];
      *(float4*)&ev[0]  = ((const float4*)er)[0];
      *(float4*)&ev[4]  = ((const float4*)er)[1];
      *(float4*)&ev[8]  = ((const float4*)er)[2];
      *(float4*)&ev[12] = ((const float4*)er)[3];
      const int cb = q * 16;
#pragma unroll
      for (int m = 0; m < 16; ++m) sA[cb + m][br] = ev[m];
    }
    __syncthreads();

    // ---- GEMM0: H1[64 x 128] = relu(E * W0 + b0) ----
    float acc[4][8];
#pragma unroll
    for (int i = 0; i < 4; ++i)
#pragma unroll
      for (int j = 0; j < 8; ++j) acc[i][j] = bias0[j];

#pragma unroll 4
    for (int k = 0; k < K0; ++k) {
      const float4 a = *(const float4*)&sA[k][tb * 4];
      const float* wr = W0 + k * NH + tl * 8;
      const float4 w0 = ((const float4*)wr)[0];
      const float4 w1 = ((const float4*)wr)[1];
      const float av[4] = {a.x, a.y, a.z, a.w};
      const float wv[8] = {w0.x, w0.y, w0.z, w0.w, w1.x, w1.y, w1.z, w1.w};
#pragma unroll
      for (int i = 0; i < 4; ++i)
#pragma unroll
        for (int j = 0; j < 8; ++j) acc[i][j] = fmaf(av[i], wv[j], acc[i][j]);
    }
#pragma unroll
    for (int i = 0; i < 4; ++i)
#pragma unroll
      for (int j = 0; j < 8; ++j) acc[i][j] = fmaxf(acc[i][j], 0.0f);

    // ---- write H1 transposed to LDS: sH[l][b_local] ----
#pragma unroll
    for (int j = 0; j < 8; ++j) {
      *(float4*)&sH[tl * 8 + j][tb * 4] =
          make_float4(acc[0][j], acc[1][j], acc[2][j], acc[3][j]);
    }
    __syncthreads();

    // ---- GEMM1: H2[64 x 128] = relu(H1 * W1 + b1) ----
    float acc2[4][8];
#pragma unroll
    for (int i = 0; i < 4; ++i)
#pragma unroll
      for (int j = 0; j < 8; ++j) acc2[i][j] = bias1[j];

#pragma unroll 4
    for (int k = 0; k < NH; ++k) {
      const float4 a = *(const float4*)&sH[k][tb * 4];
      const float* wr = W1 + k * NH + tl * 8;
      const float4 w0 = ((const float4*)wr)[0];
      const float4 w1 = ((const float4*)wr)[1];
      const float av[4] = {a.x, a.y, a.z, a.w};
      const float wv[8] = {w0.x, w0.y, w0.z, w0.w, w1.x, w1.y, w1.z, w1.w};
#pragma unroll
      for (int i = 0; i < 4; ++i)
#pragma unroll
        for (int j = 0; j < 8; ++j) acc2[i][j] = fmaf(av[i], wv[j], acc2[i][j]);
    }

    // ---- layer 2 (GEMV, in registers): y[b] = relu(H2) . w2 + b2 ----
    float part[4];
#pragma unroll
    for (int i = 0; i < 4; ++i) {
      float s = 0.0f;
#pragma unroll
      for (int j = 0; j < 8; ++j) s = fmaf(fmaxf(acc2[i][j], 0.0f), wv2[j], s);
      part[i] = s;
    }
    // reduce across the 16 l-lanes (lane bits 0..3)
#pragma unroll
    for (int m = 1; m < 16; m <<= 1)
#pragma unroll
      for (int i = 0; i < 4; ++i) part[i] += __shfl_xor(part[i], m, 64);

    if (tl == 0) {
#pragma unroll
      for (int i = 0; i < 4; ++i) {
        const float val = (part[i] + b2s) * z;
        atomicAdd(&ws[(g & (NCH - 1)) * Bsz + bbase + tb * 4 + i], val);
      }
    }
  }
}

__global__ void reduce_ws_kernel(const float* __restrict__ ws,
                                 float* __restrict__ out) {
  const int b = blockIdx.x * 256 + threadIdx.x;
  float s = 0.0f;
#pragma unroll
  for (int c = 0; c < NCH; ++c) s += ws[c * Bsz + b];
  out[b] = s;
}

extern "C" void kernel_launch(void* const* d_in, const int* in_sizes, int n_in,
                              void* d_out, int out_size, void* d_ws,
                              size_t ws_size, hipStream_t stream) {
  const int*   mains      = (const int*)d_in[0];
  const int*   pairs      = (const int*)d_in[1];
  const float* emb        = (const float*)d_in[2];
  const float* mw0        = (const float*)d_in[3];
  const float* mw1        = (const float*)d_in[4];
  const float* mw2        = (const float*)d_in[5];
  const float* mb0        = (const float*)d_in[6];
  const float* mb1        = (const float*)d_in[7];
  const float* mb2        = (const float*)d_in[8];
  const float* z_main     = (const float*)d_in[9];
  const float* pw0        = (const float*)d_in[10];
  const float* pw1        = (const float*)d_in[11];
  const float* pw2        = (const float*)d_in[12];
  const float* pb0        = (const float*)d_in[13];
  const float* pb1        = (const float*)d_in[14];
  const float* pb2        = (const float*)d_in[15];
  const float* z_pairs    = (const float*)d_in[16];
  const int*   pairs_list = (const int*)d_in[17];
  const int*   foff       = (const int*)d_in[18];
  float* ws  = (float*)d_ws;
  float* out = (float*)d_out;

  // ws partials are re-poisoned before every timed launch -> zero them here.
  zero_ws_kernel<<<(NCH * Bsz) / 256, 256, 0, stream>>>(ws);
  fused_groups_kernel<<<NBLK, 256, 0, stream>>>(
      mains, pairs, emb, mw0, mw1, mw2, mb0, mb1, mb2, z_main, pw0, pw1, pw2,
      pb0, pb1, pb2, z_pairs, pairs_list, foff, ws);
  reduce_ws_kernel<<<Bsz / 256, 256, 0, stream>>>(ws, out);
}